// Round 1
// baseline (421.160 us; speedup 1.0000x reference)
//
#include <hip/hip_runtime.h>

typedef unsigned short u16;
typedef __attribute__((ext_vector_type(8))) __bf16 bf16x8;
typedef __attribute__((ext_vector_type(4))) float f32x4;

#define D_MODEL 2048
#define SEQ 2048
#define NHEAD 16
#define HDIM 128

#define AS1 __attribute__((address_space(1)))
#define AS3 __attribute__((address_space(3)))
#define GL2LDS(g, l) __builtin_amdgcn_global_load_lds((AS1 const void*)(g), (AS3 void*)(l), 16, 0, 0)

__device__ __forceinline__ u16 f2bf(float f) {
  unsigned u = __float_as_uint(f);
  u += 0x7fff + ((u >> 16) & 1);   // RNE
  return (u16)(u >> 16);
}
__device__ __forceinline__ float bf2f(u16 h) {
  return __uint_as_float(((unsigned)h) << 16);
}

// ---------------- fp32 -> bf16 cast ----------------
__global__ __launch_bounds__(256) void k_cast(const float* __restrict__ in, u16* __restrict__ out, int n4) {
  int i = blockIdx.x * blockDim.x + threadIdx.x;
  if (i >= n4) return;
  const float4 v = reinterpret_cast<const float4*>(in)[i];
  ushort4 o;
  o.x = f2bf(v.x); o.y = f2bf(v.y); o.z = f2bf(v.z); o.w = f2bf(v.w);
  reinterpret_cast<ushort4*>(out)[i] = o;
}

// ---------------- NT GEMM: C[m,n] = sum_k A[m,k]*B[n,k], 2048^3, 128x128 tile ----------------
template<bool BF16OUT>
__device__ __forceinline__ void gemm_nt_body(const u16* __restrict__ A, const u16* __restrict__ B,
                                             void* __restrict__ C, u16* As, u16* Bs) {
  const int tn = blockIdx.x, tm = blockIdx.y;
  const int t = threadIdx.x;
  const int lane = t & 63, w = t >> 6;
  const int wr = w >> 1, wc = w & 1;
  const int lrow = lane & 15, lk = (lane >> 4) * 8;
  f32x4 acc[4][4] = {};
  for (int kt = 0; kt < D_MODEL; kt += 64) {
#pragma unroll
    for (int c = 0; c < 4; ++c) {
      const int elem = c * 2048 + t * 8;     // flat bf16 index into 128x64 tile
      const int r = elem >> 6, col = elem & 63;
      GL2LDS(A + (size_t)(tm * 128 + r) * D_MODEL + kt + col, As + c * 2048 + w * 512);
      GL2LDS(B + (size_t)(tn * 128 + r) * D_MODEL + kt + col, Bs + c * 2048 + w * 512);
    }
    asm volatile("s_waitcnt vmcnt(0)" ::: "memory");
    __syncthreads();
#pragma unroll
    for (int kk = 0; kk < 2; ++kk) {
      bf16x8 af[4], bfr[4];
#pragma unroll
      for (int i = 0; i < 4; ++i) {
        af[i]  = *(const bf16x8*)(As + (wr * 64 + i * 16 + lrow) * 64 + kk * 32 + lk);
        bfr[i] = *(const bf16x8*)(Bs + (wc * 64 + i * 16 + lrow) * 64 + kk * 32 + lk);
      }
#pragma unroll
      for (int i = 0; i < 4; ++i)
#pragma unroll
        for (int j = 0; j < 4; ++j)
          acc[i][j] = __builtin_amdgcn_mfma_f32_16x16x32_bf16(af[i], bfr[j], acc[i][j], 0, 0, 0);
    }
    __syncthreads();
  }
  // C layout (measured m89): col = lane&15, row = (lane>>4)*4 + reg
  const int crow0 = tm * 128 + wr * 64 + (lane >> 4) * 4;
  const int ccol0 = tn * 128 + wc * 64 + lrow;
#pragma unroll
  for (int i = 0; i < 4; ++i)
#pragma unroll
    for (int j = 0; j < 4; ++j)
#pragma unroll
      for (int r = 0; r < 4; ++r) {
        const size_t idx = (size_t)(crow0 + i * 16 + r) * D_MODEL + ccol0 + j * 16;
        if (BF16OUT) ((u16*)C)[idx] = f2bf(acc[i][j][r]);
        else         ((float*)C)[idx] = acc[i][j][r];
      }
}

__global__ __launch_bounds__(256) void k_gemm_qkv(const u16* Xq, const u16* Xk, const u16* Xv,
                                                  const u16* Wq, const u16* Wk, const u16* Wv,
                                                  u16* Q, u16* K, u16* V) {
  __shared__ u16 As[128 * 64], Bs[128 * 64];
  const int z = blockIdx.z;
  const u16* A = (z == 0) ? Xq : (z == 1) ? Xk : Xv;
  const u16* B = (z == 0) ? Wq : (z == 1) ? Wk : Wv;
  u16* C = (z == 0) ? Q : (z == 1) ? K : V;
  gemm_nt_body<true>(A, B, C, As, Bs);
}

__global__ __launch_bounds__(256) void k_gemm_out(const u16* A, const u16* B, float* C) {
  __shared__ u16 As[128 * 64], Bs[128 * 64];
  gemm_nt_body<false>(A, B, C, As, Bs);
}

// ---------------- RoPE (rotate_half, tiled cos/sin); Q also gets 1/sqrt(hd) ----------------
__global__ __launch_bounds__(256) void k_rope(u16* Q, u16* K) {
  const int idx = blockIdx.x * blockDim.x + threadIdx.x; // 0 .. SEQ*NHEAD*64-1
  u16* X = blockIdx.y ? K : Q;
  const float scale = blockIdx.y ? 1.0f : 0.08838834764831845f;
  const int s = idx >> 10;
  const int h = (idx >> 6) & 15;
  const int j = idx & 63;
  const float freq = __expf((float)j * -0.14391156831212787f); // -ln(10000)/64
  float sn, cs;
  sincosf((float)s * freq, &sn, &cs);
  const size_t base = (size_t)s * D_MODEL + h * HDIM + j;
  const float x1 = bf2f(X[base]), x2 = bf2f(X[base + 64]);
  X[base]      = f2bf((x1 * cs - x2 * sn) * scale);
  X[base + 64] = f2bf((x2 * cs + x1 * sn) * scale);
}

// ---------------- causal flash attention: 1 block = (head, 128 q rows), 4 waves x 32 rows ----------------
__global__ __launch_bounds__(256) void k_attn(const u16* __restrict__ Q, const u16* __restrict__ K,
                                              const u16* __restrict__ V, u16* __restrict__ O) {
  __shared__ u16 Kl[64 * 136];      // [n][d] padded (272B rows, 16B-aligned)
  __shared__ u16 Vt[128 * 72];      // [d][n] transposed, padded
  __shared__ u16 Pl[4][32 * 72];    // per-wave P, padded
  const int h = blockIdx.y;
  const int qb = blockIdx.x * 128;
  const int t = threadIdx.x;
  const int lane = t & 63, w = t >> 6;
  const int lrow = lane & 15, g = lane >> 4, lk = g * 8;

  // Q fragments in registers (Q pre-scaled by 1/sqrt(128) in RoPE)
  bf16x8 qf[2][4];
#pragma unroll
  for (int mi = 0; mi < 2; ++mi)
#pragma unroll
    for (int ks = 0; ks < 4; ++ks)
      qf[mi][ks] = *(const bf16x8*)(Q + (size_t)(qb + w * 32 + mi * 16 + lrow) * D_MODEL + h * HDIM + ks * 32 + lk);

  f32x4 accO[2][8] = {};
  float m_run[2][4], l_run[2][4];
#pragma unroll
  for (int mi = 0; mi < 2; ++mi)
#pragma unroll
    for (int r = 0; r < 4; ++r) { m_run[mi][r] = -1e30f; l_run[mi][r] = 0.f; }

  const int ntiles = (qb + 128) >> 6;
  for (int tt = 0; tt < ntiles; ++tt) {
    const int kv = tt * 64;
    // stage K (row-major) and V (transposed via register gather)
#pragma unroll
    for (int p = 0; p < 4; ++p) {
      {
        const int flat = p * 2048 + t * 8;
        const int n = flat >> 7, d0 = flat & 127;
        *(bf16x8*)(Kl + n * 136 + d0) =
            *(const bf16x8*)(K + (size_t)(kv + n) * D_MODEL + h * HDIM + d0);
      }
      {
        const int d = p * 32 + (t & 31), n0 = (t >> 5) * 8;
        bf16x8 vv;
#pragma unroll
        for (int e = 0; e < 8; ++e)
          vv[e] = ((const __bf16*)V)[(size_t)(kv + n0 + e) * D_MODEL + h * HDIM + d];
        *(bf16x8*)(Vt + d * 72 + n0) = vv;
      }
    }
    __syncthreads();

    // S = Q K^T  (32x64 per wave)
    f32x4 s[2][4] = {};
#pragma unroll
    for (int ks = 0; ks < 4; ++ks) {
      bf16x8 kf[4];
#pragma unroll
      for (int ni = 0; ni < 4; ++ni)
        kf[ni] = *(const bf16x8*)(Kl + (ni * 16 + lrow) * 136 + ks * 32 + lk);
#pragma unroll
      for (int mi = 0; mi < 2; ++mi)
#pragma unroll
        for (int ni = 0; ni < 4; ++ni)
          s[mi][ni] = __builtin_amdgcn_mfma_f32_16x16x32_bf16(qf[mi][ks], kf[ni], s[mi][ni], 0, 0, 0);
    }

    // mask + wave-parallel online softmax (16-lane groups own rows)
#pragma unroll
    for (int mi = 0; mi < 2; ++mi) {
#pragma unroll
      for (int r = 0; r < 4; ++r) {
        const int rowg = qb + w * 32 + mi * 16 + g * 4 + r;
#pragma unroll
        for (int ni = 0; ni < 4; ++ni) {
          const int colg = kv + ni * 16 + lrow;
          if (colg > rowg) s[mi][ni][r] = -1e30f;
        }
        float pm = fmaxf(fmaxf(s[mi][0][r], s[mi][1][r]), fmaxf(s[mi][2][r], s[mi][3][r]));
        pm = fmaxf(pm, __shfl_xor(pm, 1));
        pm = fmaxf(pm, __shfl_xor(pm, 2));
        pm = fmaxf(pm, __shfl_xor(pm, 4));
        pm = fmaxf(pm, __shfl_xor(pm, 8));
        const float mo = m_run[mi][r];
        const float mn = fmaxf(mo, pm);
        const float sf = __expf(mo - mn);
        float rs = 0.f;
#pragma unroll
        for (int ni = 0; ni < 4; ++ni) {
          const float p = __expf(s[mi][ni][r] - mn);
          s[mi][ni][r] = p;
          rs += p;
        }
        rs += __shfl_xor(rs, 1);
        rs += __shfl_xor(rs, 2);
        rs += __shfl_xor(rs, 4);
        rs += __shfl_xor(rs, 8);
        l_run[mi][r] = l_run[mi][r] * sf + rs;
        m_run[mi][r] = mn;
#pragma unroll
        for (int dt = 0; dt < 8; ++dt) accO[mi][dt][r] *= sf;
      }
    }

    // P (C-layout) -> per-wave LDS, then read back as A-fragments
#pragma unroll
    for (int mi = 0; mi < 2; ++mi)
#pragma unroll
      for (int ni = 0; ni < 4; ++ni)
#pragma unroll
        for (int r = 0; r < 4; ++r)
          Pl[w][(mi * 16 + g * 4 + r) * 72 + ni * 16 + lrow] = f2bf(s[mi][ni][r]);
    asm volatile("s_waitcnt lgkmcnt(0)" ::: "memory");

    // O += P V
#pragma unroll
    for (int ns = 0; ns < 2; ++ns) {
      bf16x8 pf[2];
#pragma unroll
      for (int mi = 0; mi < 2; ++mi)
        pf[mi] = *(const bf16x8*)(Pl[w] + (mi * 16 + lrow) * 72 + ns * 32 + lk);
#pragma unroll
      for (int dt = 0; dt < 8; ++dt) {
        const bf16x8 vf = *(const bf16x8*)(Vt + (dt * 16 + lrow) * 72 + ns * 32 + lk);
#pragma unroll
        for (int mi = 0; mi < 2; ++mi)
          accO[mi][dt] = __builtin_amdgcn_mfma_f32_16x16x32_bf16(pf[mi], vf, accO[mi][dt], 0, 0, 0);
      }
    }
    __syncthreads();
  }

  // epilogue: O /= l, store bf16
#pragma unroll
  for (int mi = 0; mi < 2; ++mi)
#pragma unroll
    for (int r = 0; r < 4; ++r) {
      const float inv = 1.0f / l_run[mi][r];
      const size_t row = (size_t)(qb + w * 32 + mi * 16 + g * 4 + r);
#pragma unroll
      for (int dt = 0; dt < 8; ++dt)
        O[row * D_MODEL + h * HDIM + dt * 16 + lrow] = f2bf(accO[mi][dt][r] * inv);
    }
}

// ---------------- launch ----------------
extern "C" void kernel_launch(void* const* d_in, const int* in_sizes, int n_in,
                              void* d_out, int out_size, void* d_ws, size_t ws_size,
                              hipStream_t stream) {
  const float* query = (const float*)d_in[0];
  const float* key_  = (const float*)d_in[1];
  const float* value = (const float*)d_in[2];
  const float* Wq    = (const float*)d_in[3];
  const float* Wk    = (const float*)d_in[4];
  const float* Wv    = (const float*)d_in[5];
  const float* Wo    = (const float*)d_in[6];
  float* out = (float*)d_out;

  const size_t TS = (size_t)SEQ * D_MODEL; // 4M elems per tensor
  u16* ws  = (u16*)d_ws;
  u16* bXq = ws + 0 * TS;
  u16* bXk = ws + 1 * TS;
  u16* bXv = ws + 2 * TS;
  u16* bWq = ws + 3 * TS;
  u16* bWk = ws + 4 * TS;
  u16* bWv = ws + 5 * TS;
  u16* bWo = ws + 6 * TS;
  u16* bQ  = ws + 7 * TS;
  u16* bK  = ws + 8 * TS;
  u16* bV  = ws + 9 * TS;
  u16* bA  = ws + 10 * TS;

  const int n4 = (int)(TS / 4);
  const dim3 cb(256);
  const dim3 cg(n4 / 256);
  k_cast<<<cg, cb, 0, stream>>>(query, bXq, n4);
  k_cast<<<cg, cb, 0, stream>>>(key_,  bXk, n4);
  k_cast<<<cg, cb, 0, stream>>>(value, bXv, n4);
  k_cast<<<cg, cb, 0, stream>>>(Wq, bWq, n4);
  k_cast<<<cg, cb, 0, stream>>>(Wk, bWk, n4);
  k_cast<<<cg, cb, 0, stream>>>(Wv, bWv, n4);
  k_cast<<<cg, cb, 0, stream>>>(Wo, bWo, n4);

  k_gemm_qkv<<<dim3(16, 16, 3), 256, 0, stream>>>(bXq, bXk, bXv, bWq, bWk, bWv, bQ, bK, bV);

  k_rope<<<dim3((SEQ * NHEAD * 64) / 256, 2), 256, 0, stream>>>(bQ, bK);

  k_attn<<<dim3(16, 16), 256, 0, stream>>>(bQ, bK, bV, bA);

  k_gemm_out<<<dim3(16, 16), 256, 0, stream>>>(bA, bWo, out);
}